// Round 1
// baseline (326.799 us; speedup 1.0000x reference)
//
#include <hip/hip_runtime.h>
#include <hip/hip_bf16.h>

// NonlinearReservoirCell: B=262144 rows, M=3 independent tiny MLPs
//   free_water = last_free_water + sum_n runoff
//   a1 = relu(runoff @ W1 + b1)   (256 -> 256)
//   a2 = relu(a1 @ W2 + b2)       (256 -> 128)
//   ratio = sigmoid(a2 @ W3 + b3) (128 -> 1)
//   flow = fw*ratio + last_flow*(1-ratio);  new_fw = fw - flow
// Strategy: bf16 MFMA (32x32x16), everything transposed so batch row = lane&31.
// Inter-layer transpose done fully in-register via permlane32_swap (no LDS bounce).

#define B_TOT 262144
#define M_    3
#define N_    256
#define H1_   256
#define H2_   128
#define BM_   (B_TOT * M_)

typedef __bf16 bf16_t;
typedef __bf16  bf16x8 __attribute__((ext_vector_type(8)));
typedef float   f32x16 __attribute__((ext_vector_type(16)));
typedef float   f32x4  __attribute__((ext_vector_type(4)));

__device__ __forceinline__ unsigned pack_bf2(float lo, float hi) {
  union { bf16_t b; unsigned short u; } a, c;
  a.b = (bf16_t)lo; c.b = (bf16_t)hi;
  return ((unsigned)c.u << 16) | (unsigned)a.u;
}

__device__ __forceinline__ void gload_lds16(const void* g, void* l) {
  __builtin_amdgcn_global_load_lds(
      (const __attribute__((address_space(1))) void*)g,
      (__attribute__((address_space(3))) void*)l, 16, 0, 0);
}

// ---------------------------------------------------------------------------
// Prep: transpose + cvt weights into per-lane MFMA A-fragment order (bf16).
// w1s[m][kk(16)][t(8)][lane(64)][ii(8)] = bf16(W1[m][n=16kk+8*(lane>>5)+ii][h=32t+(lane&31)])
// w2s[m][kk2(16)][t2(4)][lane(64)][ii(8)] = bf16(W2[m][h=16kk2+8*(lane>>5)+ii][k2=32t2+(lane&31)])
// ---------------------------------------------------------------------------
__global__ __launch_bounds__(256) void prep_weights(
    const float* __restrict__ W1, const float* __restrict__ W2,
    bf16_t* __restrict__ w1s, bf16_t* __restrict__ w2s)
{
  int id = blockIdx.x * 256 + threadIdx.x;
  const int NW1 = M_ * 16 * 8 * 64;   // 24576 groups of 8
  const int NW2 = M_ * 16 * 4 * 64;   // 12288 groups of 8
  if (id < NW1) {
    int lane = id & 63;
    int t    = (id >> 6) & 7;
    int kk   = (id >> 9) & 15;
    int m    = id >> 13;
    int h  = 32 * t + (lane & 31);
    int n0 = 16 * kk + 8 * (lane >> 5);
    bf16x8 v;
#pragma unroll
    for (int ii = 0; ii < 8; ++ii)
      v[ii] = (bf16_t)W1[((size_t)m * N_ + (n0 + ii)) * H1_ + h];
    *reinterpret_cast<bf16x8*>(&w1s[(size_t)id * 8]) = v;
  } else if (id < NW1 + NW2) {
    int j    = id - NW1;
    int lane = j & 63;
    int t2   = (j >> 6) & 3;
    int kk2  = (j >> 8) & 15;
    int m    = j >> 12;
    int k2 = 32 * t2 + (lane & 31);
    int h0 = 16 * kk2 + 8 * (lane >> 5);
    bf16x8 v;
#pragma unroll
    for (int ii = 0; ii < 8; ++ii)
      v[ii] = (bf16_t)W2[((size_t)m * H1_ + (h0 + ii)) * H2_ + k2];
    *reinterpret_cast<bf16x8*>(&w2s[(size_t)j * 8]) = v;
  }
}

// ---------------------------------------------------------------------------
// Main fused kernel. Block = 256 thr = 4 waves; wave owns 32 batch rows.
// grid = (B/128, M).
// ---------------------------------------------------------------------------
__global__ __launch_bounds__(256, 2) void reservoir_kernel(
    const float* __restrict__ last_flow,
    const float* __restrict__ last_fw,
    const float* __restrict__ runoff,
    const float* __restrict__ b1,
    const float* __restrict__ b2,
    const float* __restrict__ W3,
    const float* __restrict__ b3,
    const bf16_t* __restrict__ w1s,
    const bf16_t* __restrict__ w2s,
    float* __restrict__ out)
{
  __shared__ alignas(16) bf16_t sW1[2][4096];  // 8 KB per buf: panel kk of W1
  __shared__ alignas(16) bf16_t sW2[2][2048];  // 4 KB per buf: panel kk2 of W2
  __shared__ alignas(16) float  sB1[H1_];
  __shared__ alignas(16) float  sB2[H2_];
  __shared__ alignas(16) float  sW3[H2_];

  const int tid  = threadIdx.x;
  const int lane = tid & 63;
  const int wv   = tid >> 6;
  const int m    = blockIdx.y;
  const int hi   = lane >> 5;
  const int r    = lane & 31;
  const int row  = blockIdx.x * 128 + wv * 32 + r;

  const bf16_t* w1base = w1s + (size_t)m * 65536;
  const bf16_t* w2base = w2s + (size_t)m * 32768;

  auto stage_w1 = [&](int kk, int buf) {
#pragma unroll
    for (int c = 0; c < 2; ++c) {
      int chunk = wv * 2 + c;  // 8 chunks of 1 KB
      gload_lds16(w1base + (size_t)kk * 4096 + chunk * 512 + lane * 8,
                  &sW1[buf][chunk * 512]);
    }
  };
  auto stage_w2 = [&](int kk2, int buf) {
    gload_lds16(w2base + (size_t)kk2 * 2048 + wv * 512 + lane * 8,
                &sW2[buf][wv * 512]);
  };

  // stage biases / W3 + first W1 panel
  if (tid < H1_) sB1[tid] = b1[m * H1_ + tid];
  if (tid < H2_) { sB2[tid] = b2[m * H2_ + tid]; sW3[tid] = W3[m * H2_ + tid]; }
  stage_w1(0, 0);
  __syncthreads();

  // ---------------- Layer 1: a1^T[h][r] ----------------
  // C-frag: col = lane&31 = batch row r; row(h within 32-tile) = (e&3)+8*(e>>2)+4*hi
  f32x16 acc1[8];
#pragma unroll
  for (int t = 0; t < 8; ++t) {
#pragma unroll
    for (int g2 = 0; g2 < 4; ++g2) {
      f32x4 bv = *reinterpret_cast<const f32x4*>(&sB1[32 * t + 8 * g2 + 4 * hi]);
      acc1[t][4 * g2 + 0] = bv[0];
      acc1[t][4 * g2 + 1] = bv[1];
      acc1[t][4 * g2 + 2] = bv[2];
      acc1[t][4 * g2 + 3] = bv[3];
    }
  }

  float rsum = 0.f;
  const float* rowptr = runoff + ((size_t)row * M_ + m) * N_;

#pragma unroll
  for (int kk = 0; kk < 16; ++kk) {
    const int cb = kk & 1;
    if (kk < 15) stage_w1(kk + 1, cb ^ 1);
    else         stage_w2(0, 0);          // prefetch first W2 panel in the slot

    // B-frag: B[k = 8*hi+ii][col=r] = runoff[row][16kk + 8hi + ii]
    f32x4 qa = *reinterpret_cast<const f32x4*>(&rowptr[16 * kk + 8 * hi]);
    f32x4 qb = *reinterpret_cast<const f32x4*>(&rowptr[16 * kk + 8 * hi + 4]);
    rsum += qa[0] + qa[1] + qa[2] + qa[3] + qb[0] + qb[1] + qb[2] + qb[3];
    bf16x8 bfrag;
    bfrag[0] = (bf16_t)qa[0]; bfrag[1] = (bf16_t)qa[1];
    bfrag[2] = (bf16_t)qa[2]; bfrag[3] = (bf16_t)qa[3];
    bfrag[4] = (bf16_t)qb[0]; bfrag[5] = (bf16_t)qb[1];
    bfrag[6] = (bf16_t)qb[2]; bfrag[7] = (bf16_t)qb[3];

#pragma unroll
    for (int t = 0; t < 8; ++t) {
      bf16x8 afrag = *reinterpret_cast<const bf16x8*>(&sW1[cb][t * 512 + lane * 8]);
      acc1[t] = __builtin_amdgcn_mfma_f32_32x32x16_bf16(afrag, bfrag, acc1[t], 0, 0, 0);
    }
    __syncthreads();
  }

  // -------- inter-layer: relu + bf16 pack (a1 stays in registers) --------
  // P[t][q][v][s] packs C-regs (8q+4v+2s, +1) -> what dest lanes with hi=v need
  unsigned P[8][2][2][2];
#pragma unroll
  for (int t = 0; t < 8; ++t)
#pragma unroll
    for (int q = 0; q < 2; ++q)
#pragma unroll
      for (int v = 0; v < 2; ++v)
#pragma unroll
        for (int s = 0; s < 2; ++s) {
          int e = 8 * q + 4 * v + 2 * s;
          P[t][q][v][s] = pack_bf2(fmaxf(acc1[t][e], 0.f),
                                   fmaxf(acc1[t][e + 1], 0.f));
        }

  // ---------------- Layer 2: a2^T[k2][r] ----------------
  f32x16 acc2[4];
#pragma unroll
  for (int t2 = 0; t2 < 4; ++t2) {
#pragma unroll
    for (int g2 = 0; g2 < 4; ++g2) {
      f32x4 bv = *reinterpret_cast<const f32x4*>(&sB2[32 * t2 + 8 * g2 + 4 * hi]);
      acc2[t2][4 * g2 + 0] = bv[0];
      acc2[t2][4 * g2 + 1] = bv[1];
      acc2[t2][4 * g2 + 2] = bv[2];
      acc2[t2][4 * g2 + 3] = bv[3];
    }
  }

#pragma unroll
  for (int kk2 = 0; kk2 < 16; ++kk2) {
    const int cb = kk2 & 1;
    if (kk2 < 15) stage_w2(kk2 + 1, cb ^ 1);
    const int t = kk2 >> 1, q = kk2 & 1;

    // B2-frag via 2 permlane32_swap: dwords {X'(s0), X'(s1), Y'(s0), Y'(s1)}
    auto r0 = __builtin_amdgcn_permlane32_swap(P[t][q][0][0], P[t][q][1][0], false, false);
    auto r1 = __builtin_amdgcn_permlane32_swap(P[t][q][0][1], P[t][q][1][1], false, false);
    union { unsigned u[4]; bf16x8 v; } bb;
    bb.u[0] = r0[0]; bb.u[1] = r1[0]; bb.u[2] = r0[1]; bb.u[3] = r1[1];

#pragma unroll
    for (int t2 = 0; t2 < 4; ++t2) {
      bf16x8 afrag = *reinterpret_cast<const bf16x8*>(&sW2[cb][t2 * 512 + lane * 8]);
      acc2[t2] = __builtin_amdgcn_mfma_f32_32x32x16_bf16(afrag, bb.v, acc2[t2], 0, 0, 0);
    }
    __syncthreads();
  }

  // ---------------- Layer 3: dot with W3, sigmoid, blend ----------------
  float part = 0.f;
#pragma unroll
  for (int t2 = 0; t2 < 4; ++t2) {
#pragma unroll
    for (int g2 = 0; g2 < 4; ++g2) {
      f32x4 w3v = *reinterpret_cast<const f32x4*>(&sW3[32 * t2 + 8 * g2 + 4 * hi]);
      part += fmaxf(acc2[t2][4 * g2 + 0], 0.f) * w3v[0]
            + fmaxf(acc2[t2][4 * g2 + 1], 0.f) * w3v[1]
            + fmaxf(acc2[t2][4 * g2 + 2], 0.f) * w3v[2]
            + fmaxf(acc2[t2][4 * g2 + 3], 0.f) * w3v[3];
    }
  }
  part += __shfl_xor(part, 32, 64);  // combine hi halves (k2 mod 8 split)
  rsum += __shfl_xor(rsum, 32, 64);  // combine n mod 16 split

  const float x     = part + b3[m];
  const float ratio = 1.0f / (1.0f + __expf(-x));
  const size_t oi   = (size_t)row * M_ + m;
  const float fw    = last_fw[oi] + rsum;
  const float lf    = last_flow[oi];
  const float flow  = fw * ratio + lf * (1.0f - ratio);
  if (hi == 0) {
    out[oi]        = fw - flow;   // new_free_water
    out[BM_ + oi]  = flow;        // flow
  }
}

// ---------------------------------------------------------------------------
extern "C" void kernel_launch(void* const* d_in, const int* in_sizes, int n_in,
                              void* d_out, int out_size, void* d_ws, size_t ws_size,
                              hipStream_t stream) {
  const float* last_flow = (const float*)d_in[0];
  const float* last_fw   = (const float*)d_in[1];
  const float* runoff    = (const float*)d_in[2];
  const float* W1 = (const float*)d_in[3];
  const float* b1 = (const float*)d_in[4];
  const float* W2 = (const float*)d_in[5];
  const float* b2 = (const float*)d_in[6];
  const float* W3 = (const float*)d_in[7];
  const float* b3 = (const float*)d_in[8];
  float* out = (float*)d_out;

  // ws: W1T bf16 (3*65536 elems = 384 KB) then W2T bf16 (3*32768 = 192 KB)
  bf16_t* w1s = (bf16_t*)d_ws;
  bf16_t* w2s = w1s + (size_t)M_ * 65536;

  prep_weights<<<144, 256, 0, stream>>>(W1, W2, w1s, w2s);

  dim3 grid(B_TOT / 128, M_);
  reservoir_kernel<<<grid, 256, 0, stream>>>(last_flow, last_fw, runoff,
                                             b1, b2, W3, b3, w1s, w2s, out);
}

// Round 2
// 289.061 us; speedup vs baseline: 1.1306x; 1.1306x over previous
//
#include <hip/hip_runtime.h>
#include <hip/hip_bf16.h>

// NonlinearReservoirCell: B=262144 rows, M=3 independent tiny MLPs
//   free_water = last_free_water + sum_n runoff
//   a1 = relu(runoff @ W1 + b1)   (256 -> 256)
//   a2 = relu(a1 @ W2 + b2)       (256 -> 128)
//   ratio = sigmoid(a2 @ W3 + b3) (128 -> 1)
//   flow = fw*ratio + last_flow*(1-ratio);  new_fw = fw - flow
// bf16 MFMA (32x32x16), batch row = lane&31 (swapped orientation).
// R1: runoff staged through LDS (coalesced line-granular global reads,
//     XOR-swizzled panel to kill the 32-way bank conflict), W1 staged in
//     2-panel groups -> 8 barriers in layer 1 instead of 16.

#define B_TOT 262144
#define M_    3
#define N_    256
#define H1_   256
#define H2_   128
#define BM_   (B_TOT * M_)

typedef __bf16 bf16_t;
typedef __bf16  bf16x8 __attribute__((ext_vector_type(8)));
typedef float   f32x16 __attribute__((ext_vector_type(16)));
typedef float   f32x4  __attribute__((ext_vector_type(4)));

__device__ __forceinline__ unsigned pack_bf2(float lo, float hi) {
  union { bf16_t b; unsigned short u; } a, c;
  a.b = (bf16_t)lo; c.b = (bf16_t)hi;
  return ((unsigned)c.u << 16) | (unsigned)a.u;
}

__device__ __forceinline__ void gload_lds16(const void* g, void* l) {
  __builtin_amdgcn_global_load_lds(
      (const __attribute__((address_space(1))) void*)g,
      (__attribute__((address_space(3))) void*)l, 16, 0, 0);
}

// ---------------------------------------------------------------------------
// Prep: transpose + cvt weights into per-lane MFMA A-fragment order (bf16).
// w1s[m][kk(16)][t(8)][lane(64)][ii(8)] = bf16(W1[m][n=16kk+8*(lane>>5)+ii][h=32t+(lane&31)])
// w2s[m][kk2(16)][t2(4)][lane(64)][ii(8)] = bf16(W2[m][h=16kk2+8*(lane>>5)+ii][k2=32t2+(lane&31)])
// ---------------------------------------------------------------------------
__global__ __launch_bounds__(256) void prep_weights(
    const float* __restrict__ W1, const float* __restrict__ W2,
    bf16_t* __restrict__ w1s, bf16_t* __restrict__ w2s)
{
  int id = blockIdx.x * 256 + threadIdx.x;
  const int NW1 = M_ * 16 * 8 * 64;   // 24576 groups of 8
  const int NW2 = M_ * 16 * 4 * 64;   // 12288 groups of 8
  if (id < NW1) {
    int lane = id & 63;
    int t    = (id >> 6) & 7;
    int kk   = (id >> 9) & 15;
    int m    = id >> 13;
    int h  = 32 * t + (lane & 31);
    int n0 = 16 * kk + 8 * (lane >> 5);
    bf16x8 v;
#pragma unroll
    for (int ii = 0; ii < 8; ++ii)
      v[ii] = (bf16_t)W1[((size_t)m * N_ + (n0 + ii)) * H1_ + h];
    *reinterpret_cast<bf16x8*>(&w1s[(size_t)id * 8]) = v;
  } else if (id < NW1 + NW2) {
    int j    = id - NW1;
    int lane = j & 63;
    int t2   = (j >> 6) & 3;
    int kk2  = (j >> 8) & 15;
    int m    = j >> 12;
    int k2 = 32 * t2 + (lane & 31);
    int h0 = 16 * kk2 + 8 * (lane >> 5);
    bf16x8 v;
#pragma unroll
    for (int ii = 0; ii < 8; ++ii)
      v[ii] = (bf16_t)W2[((size_t)m * H1_ + (h0 + ii)) * H2_ + k2];
    *reinterpret_cast<bf16x8*>(&w2s[(size_t)j * 8]) = v;
  }
}

// ---------------------------------------------------------------------------
// Main fused kernel. Block = 256 thr = 4 waves; wave owns 32 batch rows.
// grid = (B/128, M).
// ---------------------------------------------------------------------------
__global__ __launch_bounds__(256, 2) void reservoir_kernel(
    const float* __restrict__ last_flow,
    const float* __restrict__ last_fw,
    const float* __restrict__ runoff,
    const float* __restrict__ b1,
    const float* __restrict__ b2,
    const float* __restrict__ W3,
    const float* __restrict__ b3,
    const bf16_t* __restrict__ w1s,
    const bf16_t* __restrict__ w2s,
    float* __restrict__ out)
{
  // Runoff panel: [128 rows][32 floats], XOR-swizzled in 16-B granules:
  //   phys_granule = logical_granule ^ (row & 7)
  __shared__ alignas(16) float  sR[2][128 * 32];   // 2 x 16 KB
  __shared__ alignas(16) bf16_t sW1[2][8192];      // 2 x 16 KB (2 kk-panels)
  __shared__ alignas(16) bf16_t sW2[2][2048];      // 2 x 4 KB
  __shared__ alignas(16) float  sB1[H1_];
  __shared__ alignas(16) float  sB2[H2_];
  __shared__ alignas(16) float  sW3[H2_];

  const int tid  = threadIdx.x;
  const int lane = tid & 63;
  const int wv   = tid >> 6;
  const int m    = blockIdx.y;
  const int hi   = lane >> 5;
  const int r    = lane & 31;
  const int r7   = r & 7;
  const int row0 = blockIdx.x * 128;
  const int row  = row0 + wv * 32 + r;

  // staging-lane decomposition for sR: 8 rows x 8 granules per instruction
  const int l3 = lane >> 3;          // row within 8-row slab
  const int gsw = (lane & 7) ^ l3;   // logical granule feeding phys slot lane&7

  const bf16_t* w1base = w1s + (size_t)m * 65536;
  const bf16_t* w2base = w2s + (size_t)m * 32768;

  auto stage_R = [&](int g, int buf) {     // panel g: cols 32g..32g+31
#pragma unroll
    for (int c = 0; c < 4; ++c) {
      int slab = wv * 4 + c;               // 16 slabs of 8 rows
      const float* src = runoff
          + ((size_t)(row0 + slab * 8 + l3) * M_ + m) * N_ + 32 * g + 4 * gsw;
      gload_lds16(src, &sR[buf][slab * 256]);
    }
  };
  auto stage_w1g = [&](int g, int buf) {   // panels 2g,2g+1: 16 KB
#pragma unroll
    for (int c = 0; c < 4; ++c) {
      int chunk = wv * 4 + c;              // 16 chunks of 1 KB
      gload_lds16(w1base + (size_t)g * 8192 + chunk * 512 + lane * 8,
                  &sW1[buf][chunk * 512]);
    }
  };
  auto stage_w2 = [&](int kk2, int buf) {
    gload_lds16(w2base + (size_t)kk2 * 2048 + wv * 512 + lane * 8,
                &sW2[buf][wv * 512]);
  };

  // prologue: biases, first runoff panel, first W1 group
  sB1[tid] = b1[m * H1_ + tid];
  if (tid < H2_) { sB2[tid] = b2[m * H2_ + tid]; sW3[tid] = W3[m * H2_ + tid]; }
  stage_R(0, 0);
  stage_w1g(0, 0);
  __syncthreads();

  // ---------------- Layer 1: a1^T[h][r] ----------------
  f32x16 acc1[8];
#pragma unroll
  for (int t = 0; t < 8; ++t) {
#pragma unroll
    for (int g2 = 0; g2 < 4; ++g2) {
      f32x4 bv = *reinterpret_cast<const f32x4*>(&sB1[32 * t + 8 * g2 + 4 * hi]);
      acc1[t][4 * g2 + 0] = bv[0];
      acc1[t][4 * g2 + 1] = bv[1];
      acc1[t][4 * g2 + 2] = bv[2];
      acc1[t][4 * g2 + 3] = bv[3];
    }
  }

  float rsum = 0.f;
  const float* rrow_base_off = nullptr; (void)rrow_base_off;

#pragma unroll
  for (int g = 0; g < 8; ++g) {
    const int cb = g & 1;
    if (g < 7) { stage_R(g + 1, cb ^ 1); stage_w1g(g + 1, cb ^ 1); }
    else       { stage_w2(0, 0); }   // prefetch first W2 panel

#pragma unroll
    for (int q = 0; q < 2; ++q) {    // kk = 2g + q
      const float* rb = &sR[cb][(wv * 32 + r) * 32];
      f32x4 qa = *reinterpret_cast<const f32x4*>(&rb[((4 * q + 2 * hi + 0) ^ r7) * 4]);
      f32x4 qb = *reinterpret_cast<const f32x4*>(&rb[((4 * q + 2 * hi + 1) ^ r7) * 4]);
      rsum += qa[0] + qa[1] + qa[2] + qa[3] + qb[0] + qb[1] + qb[2] + qb[3];
      bf16x8 bfrag;
      bfrag[0] = (bf16_t)qa[0]; bfrag[1] = (bf16_t)qa[1];
      bfrag[2] = (bf16_t)qa[2]; bfrag[3] = (bf16_t)qa[3];
      bfrag[4] = (bf16_t)qb[0]; bfrag[5] = (bf16_t)qb[1];
      bfrag[6] = (bf16_t)qb[2]; bfrag[7] = (bf16_t)qb[3];

#pragma unroll
      for (int t = 0; t < 8; ++t) {
        bf16x8 afrag = *reinterpret_cast<const bf16x8*>(
            &sW1[cb][q * 4096 + t * 512 + lane * 8]);
        acc1[t] = __builtin_amdgcn_mfma_f32_32x32x16_bf16(afrag, bfrag, acc1[t], 0, 0, 0);
      }
    }
    __syncthreads();
  }

  // -------- inter-layer: relu + bf16 pack (a1 stays in registers) --------
  unsigned P[8][2][2][2];
#pragma unroll
  for (int t = 0; t < 8; ++t)
#pragma unroll
    for (int q = 0; q < 2; ++q)
#pragma unroll
      for (int v = 0; v < 2; ++v)
#pragma unroll
        for (int s = 0; s < 2; ++s) {
          int e = 8 * q + 4 * v + 2 * s;
          P[t][q][v][s] = pack_bf2(fmaxf(acc1[t][e], 0.f),
                                   fmaxf(acc1[t][e + 1], 0.f));
        }

  // ---------------- Layer 2: a2^T[k2][r] ----------------
  f32x16 acc2[4];
#pragma unroll
  for (int t2 = 0; t2 < 4; ++t2) {
#pragma unroll
    for (int g2 = 0; g2 < 4; ++g2) {
      f32x4 bv = *reinterpret_cast<const f32x4*>(&sB2[32 * t2 + 8 * g2 + 4 * hi]);
      acc2[t2][4 * g2 + 0] = bv[0];
      acc2[t2][4 * g2 + 1] = bv[1];
      acc2[t2][4 * g2 + 2] = bv[2];
      acc2[t2][4 * g2 + 3] = bv[3];
    }
  }

#pragma unroll
  for (int kk2 = 0; kk2 < 16; ++kk2) {
    const int cb = kk2 & 1;
    if (kk2 < 15) stage_w2(kk2 + 1, cb ^ 1);
    const int t = kk2 >> 1, q = kk2 & 1;

    // B2-frag via 2 permlane32_swap
    auto r0 = __builtin_amdgcn_permlane32_swap(P[t][q][0][0], P[t][q][1][0], false, false);
    auto r1 = __builtin_amdgcn_permlane32_swap(P[t][q][0][1], P[t][q][1][1], false, false);
    union { unsigned u[4]; bf16x8 v; } bb;
    bb.u[0] = r0[0]; bb.u[1] = r1[0]; bb.u[2] = r0[1]; bb.u[3] = r1[1];

#pragma unroll
    for (int t2 = 0; t2 < 4; ++t2) {
      bf16x8 afrag = *reinterpret_cast<const bf16x8*>(
          &sW2[cb][t2 * 512 + lane * 8]);
      acc2[t2] = __builtin_amdgcn_mfma_f32_32x32x16_bf16(afrag, bb.v, acc2[t2], 0, 0, 0);
    }
    __syncthreads();
  }

  // ---------------- Layer 3: dot with W3, sigmoid, blend ----------------
  float part = 0.f;
#pragma unroll
  for (int t2 = 0; t2 < 4; ++t2) {
#pragma unroll
    for (int g2 = 0; g2 < 4; ++g2) {
      f32x4 w3v = *reinterpret_cast<const f32x4*>(&sW3[32 * t2 + 8 * g2 + 4 * hi]);
      part += fmaxf(acc2[t2][4 * g2 + 0], 0.f) * w3v[0]
            + fmaxf(acc2[t2][4 * g2 + 1], 0.f) * w3v[1]
            + fmaxf(acc2[t2][4 * g2 + 2], 0.f) * w3v[2]
            + fmaxf(acc2[t2][4 * g2 + 3], 0.f) * w3v[3];
    }
  }
  part += __shfl_xor(part, 32, 64);  // combine k2-mod-8 halves
  rsum += __shfl_xor(rsum, 32, 64);  // combine n-mod-16 halves

  const float x     = part + b3[m];
  const float ratio = 1.0f / (1.0f + __expf(-x));
  const size_t oi   = (size_t)row * M_ + m;
  const float fw    = last_fw[oi] + rsum;
  const float lf    = last_flow[oi];
  const float flow  = fw * ratio + lf * (1.0f - ratio);
  if (hi == 0) {
    out[oi]        = fw - flow;   // new_free_water
    out[BM_ + oi]  = flow;        // flow
  }
}

// ---------------------------------------------------------------------------
extern "C" void kernel_launch(void* const* d_in, const int* in_sizes, int n_in,
                              void* d_out, int out_size, void* d_ws, size_t ws_size,
                              hipStream_t stream) {
  const float* last_flow = (const float*)d_in[0];
  const float* last_fw   = (const float*)d_in[1];
  const float* runoff    = (const float*)d_in[2];
  const float* W1 = (const float*)d_in[3];
  const float* b1 = (const float*)d_in[4];
  const float* W2 = (const float*)d_in[5];
  const float* b2 = (const float*)d_in[6];
  const float* W3 = (const float*)d_in[7];
  const float* b3 = (const float*)d_in[8];
  float* out = (float*)d_out;

  bf16_t* w1s = (bf16_t*)d_ws;                    // 3*65536 bf16 = 384 KB
  bf16_t* w2s = w1s + (size_t)M_ * 65536;         // 3*32768 bf16 = 192 KB

  prep_weights<<<144, 256, 0, stream>>>(W1, W2, w1s, w2s);

  dim3 grid(B_TOT / 128, M_);
  reservoir_kernel<<<grid, 256, 0, stream>>>(last_flow, last_fw, runoff,
                                             b1, b2, W3, b3, w1s, w2s, out);
}

// Round 3
// 284.903 us; speedup vs baseline: 1.1471x; 1.0146x over previous
//
#include <hip/hip_runtime.h>
#include <hip/hip_bf16.h>

// NonlinearReservoirCell: B=262144 rows, M=3 independent tiny MLPs
//   free_water = last_free_water + sum_n runoff
//   a1 = relu(runoff @ W1 + b1)   (256 -> 256)
//   a2 = relu(a1 @ W2 + b2)       (256 -> 128)
//   ratio = sigmoid(a2 @ W3 + b3) (128 -> 1)
//   flow = fw*ratio + last_flow*(1-ratio);  new_fw = fw - flow
// bf16 MFMA (32x32x16), batch row = lane&31 (swapped orientation).
// R3: persistent blocks (grid 768, 3/CU, 8 units of 128 rows each).
//     W2 fully LDS-resident (layer2 = zero mem ops, zero barriers).
//     R ring-3 / W1 ring-2 with counted s_waitcnt vmcnt(8) + raw s_barrier
//     (never vmcnt(0) in the loop) -> prefetch stream crosses unit
//     boundaries, HBM stays busy through layer2/3.

#define B_TOT 262144
#define M_    3
#define N_    256
#define H1_   256
#define H2_   128
#define BM_   (B_TOT * M_)

typedef __bf16 bf16_t;
typedef __bf16  bf16x8 __attribute__((ext_vector_type(8)));
typedef float   f32x16 __attribute__((ext_vector_type(16)));
typedef float   f32x4  __attribute__((ext_vector_type(4)));

__device__ __forceinline__ unsigned pack_bf2(float lo, float hi) {
  union { bf16_t b; unsigned short u; } a, c;
  a.b = (bf16_t)lo; c.b = (bf16_t)hi;
  return ((unsigned)c.u << 16) | (unsigned)a.u;
}

__device__ __forceinline__ void gload_lds16(const void* g, void* l) {
  __builtin_amdgcn_global_load_lds(
      (const __attribute__((address_space(1))) void*)g,
      (__attribute__((address_space(3))) void*)l, 16, 0, 0);
}

// ---------------------------------------------------------------------------
// Prep: transpose + cvt weights into per-lane MFMA A-fragment order (bf16).
// w1s[m][kk(16)][t(8)][lane(64)][ii(8)] = bf16(W1[m][n=16kk+8*(lane>>5)+ii][h=32t+(lane&31)])
// w2s[m][kk2(16)][t2(4)][lane(64)][ii(8)] = bf16(W2[m][h=16kk2+8*(lane>>5)+ii][k2=32t2+(lane&31)])
// ---------------------------------------------------------------------------
__global__ __launch_bounds__(256) void prep_weights(
    const float* __restrict__ W1, const float* __restrict__ W2,
    bf16_t* __restrict__ w1s, bf16_t* __restrict__ w2s)
{
  int id = blockIdx.x * 256 + threadIdx.x;
  const int NW1 = M_ * 16 * 8 * 64;   // 24576 groups of 8
  const int NW2 = M_ * 16 * 4 * 64;   // 12288 groups of 8
  if (id < NW1) {
    int lane = id & 63;
    int t    = (id >> 6) & 7;
    int kk   = (id >> 9) & 15;
    int m    = id >> 13;
    int h  = 32 * t + (lane & 31);
    int n0 = 16 * kk + 8 * (lane >> 5);
    bf16x8 v;
#pragma unroll
    for (int ii = 0; ii < 8; ++ii)
      v[ii] = (bf16_t)W1[((size_t)m * N_ + (n0 + ii)) * H1_ + h];
    *reinterpret_cast<bf16x8*>(&w1s[(size_t)id * 8]) = v;
  } else if (id < NW1 + NW2) {
    int j    = id - NW1;
    int lane = j & 63;
    int t2   = (j >> 6) & 3;
    int kk2  = (j >> 8) & 15;
    int m    = j >> 12;
    int k2 = 32 * t2 + (lane & 31);
    int h0 = 16 * kk2 + 8 * (lane >> 5);
    bf16x8 v;
#pragma unroll
    for (int ii = 0; ii < 8; ++ii)
      v[ii] = (bf16_t)W2[((size_t)m * H1_ + (h0 + ii)) * H2_ + k2];
    *reinterpret_cast<bf16x8*>(&w2s[(size_t)j * 8]) = v;
  }
}

// ---------------------------------------------------------------------------
// Main fused kernel. Block = 256 thr = 4 waves; block owns 1024 rows x 1 m
// = 8 units of 128 rows. grid = 768 (256 blocks per m), 1 block/CU resident.
// ---------------------------------------------------------------------------
__global__ __launch_bounds__(256, 1) void reservoir_kernel(
    const float* __restrict__ last_flow,
    const float* __restrict__ last_fw,
    const float* __restrict__ runoff,
    const float* __restrict__ b1,
    const float* __restrict__ b2,
    const float* __restrict__ W3,
    const float* __restrict__ b3,
    const bf16_t* __restrict__ w1s,
    const bf16_t* __restrict__ w2s,
    float* __restrict__ out)
{
  // R panel: [128 rows][32 floats], XOR-swizzled in 16-B granules
  // (phys_granule = logical ^ (row&7)). 16 KB per panel, ring of 3.
  __shared__ alignas(16) float  sR[3][128 * 32];   // 48 KB
  __shared__ alignas(16) bf16_t sW1[2][8192];      // 32 KB (16 KB = 2 kk-panels)
  __shared__ alignas(16) bf16_t sW2[16 * 2048];    // 64 KB resident (all kk2)
  __shared__ alignas(16) float  sB1[H1_];
  __shared__ alignas(16) float  sB2[H2_];
  __shared__ alignas(16) float  sW3[H2_];

  const int tid  = threadIdx.x;
  const int lane = tid & 63;
  const int wv   = tid >> 6;
  const int hi   = lane >> 5;
  const int r    = lane & 31;
  const int r7   = r & 7;
  const int l3   = lane >> 3;          // row within 8-row slab (staging)
  const int gsw  = (lane & 7) ^ l3;    // logical granule for phys slot lane&7

  const int bidx  = blockIdx.x;        // 0..767
  const int m     = bidx >> 8;         // 0..2
  const int rbase = (bidx & 255) * 1024;

  const bf16_t* w1base = w1s + (size_t)m * 65536;
  const bf16_t* w2base = w2s + (size_t)m * 32768;

  // ---- staging (issue only; waits are explicit counted vmcnt) ----
  auto stage_R = [&](int ai) {               // ai = unit*8 + g, ring slot ai%3
    int aic  = ai < 63 ? ai : 63;            // clamp (tail re-reads are L2-hot)
    int row0 = rbase + (aic >> 3) * 128;
    int g    = aic & 7;
    float* dst = &sR[ai % 3][0];
#pragma unroll
    for (int c = 0; c < 4; ++c) {
      int slab = wv * 4 + c;                 // 16 slabs of 8 rows
      const float* src = runoff
          + ((size_t)(row0 + slab * 8 + l3) * M_ + m) * N_ + 32 * g + 4 * gsw;
      gload_lds16(src, dst + slab * 256);
    }
  };
  auto stage_W1 = [&](int wai) {             // panel-pair g = wai&7, slot wai%2
    int g = wai & 7;
    bf16_t* dst = &sW1[wai & 1][0];
#pragma unroll
    for (int c = 0; c < 4; ++c) {
      int chunk = wv * 4 + c;                // 16 chunks of 1 KB
      gload_lds16(w1base + (size_t)g * 8192 + chunk * 512 + lane * 8,
                  dst + chunk * 512);
    }
  };

  // ---- prologue: R(0..2), W1(0..1), all of W2, biases; one full drain ----
  stage_R(0);  stage_W1(0);
  stage_R(1);  stage_W1(1);
  stage_R(2);
#pragma unroll
  for (int i = 0; i < 16; ++i) {             // W2: 64 chunks of 1 KB
    int chunk = wv * 16 + i;
    gload_lds16(w2base + (size_t)chunk * 512 + lane * 8, &sW2[chunk * 512]);
  }
  sB1[tid] = b1[m * H1_ + tid];
  if (tid < H2_) { sB2[tid] = b2[m * H2_ + tid]; sW3[tid] = W3[m * H2_ + tid]; }
  __syncthreads();                            // full drain ONCE per block

  for (int u = 0; u < 8; ++u) {
    const int row = rbase + u * 128 + wv * 32 + r;

    // ---------------- Layer 1: a1^T[h][r] ----------------
    f32x16 acc1[8];
#pragma unroll
    for (int t = 0; t < 8; ++t) {
#pragma unroll
      for (int g2 = 0; g2 < 4; ++g2) {
        f32x4 bv = *reinterpret_cast<const f32x4*>(&sB1[32 * t + 8 * g2 + 4 * hi]);
        acc1[t][4 * g2 + 0] = bv[0];
        acc1[t][4 * g2 + 1] = bv[1];
        acc1[t][4 * g2 + 2] = bv[2];
        acc1[t][4 * g2 + 3] = bv[3];
      }
    }
    float rsum = 0.f;

    for (int g = 0; g < 8; ++g) {
      const int ai = u * 8 + g;
      // steady state: after newest needed op (W1(ai), issued end of ai-2)
      // exactly one issue-group [R(ai+2),W1(ai+1)] = 8 ops is newer.
      asm volatile("s_waitcnt vmcnt(8)" ::: "memory");
      __builtin_amdgcn_sched_barrier(0);
      __builtin_amdgcn_s_barrier();          // all waves' panels visible

      const float*  rp = &sR[ai % 3][(wv * 32 + r) * 32];
      const bf16_t* wp = &sW1[ai & 1][0];
#pragma unroll
      for (int q = 0; q < 2; ++q) {          // kk = 2g + q
        f32x4 qa = *reinterpret_cast<const f32x4*>(&rp[((4 * q + 2 * hi + 0) ^ r7) * 4]);
        f32x4 qb = *reinterpret_cast<const f32x4*>(&rp[((4 * q + 2 * hi + 1) ^ r7) * 4]);
        rsum += qa[0] + qa[1] + qa[2] + qa[3] + qb[0] + qb[1] + qb[2] + qb[3];
        bf16x8 bfrag;
        bfrag[0] = (bf16_t)qa[0]; bfrag[1] = (bf16_t)qa[1];
        bfrag[2] = (bf16_t)qa[2]; bfrag[3] = (bf16_t)qa[3];
        bfrag[4] = (bf16_t)qb[0]; bfrag[5] = (bf16_t)qb[1];
        bfrag[6] = (bf16_t)qb[2]; bfrag[7] = (bf16_t)qb[3];
#pragma unroll
        for (int t = 0; t < 8; ++t) {
          bf16x8 afrag = *reinterpret_cast<const bf16x8*>(
              &wp[q * 4096 + t * 512 + lane * 8]);
          acc1[t] = __builtin_amdgcn_mfma_f32_32x32x16_bf16(afrag, bfrag, acc1[t], 0, 0, 0);
        }
      }

      __builtin_amdgcn_s_barrier();          // everyone done with slots we reuse
      stage_R(ai + 3);                       // slot (ai+3)%3 = ai%3, just freed
      stage_W1(ai + 2);                      // slot (ai+2)%2 = ai%2, just freed
    }

    // -------- inter-layer: relu + bf16 pack (a1 stays in registers) --------
    unsigned P[8][2][2][2];
#pragma unroll
    for (int t = 0; t < 8; ++t)
#pragma unroll
      for (int q = 0; q < 2; ++q)
#pragma unroll
        for (int v = 0; v < 2; ++v)
#pragma unroll
          for (int s = 0; s < 2; ++s) {
            int e = 8 * q + 4 * v + 2 * s;
            P[t][q][v][s] = pack_bf2(fmaxf(acc1[t][e], 0.f),
                                     fmaxf(acc1[t][e + 1], 0.f));
          }

    // ---------------- Layer 2: a2^T[k2][r]  (LDS-resident W2, no barriers) --
    f32x16 acc2[4];
#pragma unroll
    for (int t2 = 0; t2 < 4; ++t2) {
#pragma unroll
      for (int g2 = 0; g2 < 4; ++g2) {
        f32x4 bv = *reinterpret_cast<const f32x4*>(&sB2[32 * t2 + 8 * g2 + 4 * hi]);
        acc2[t2][4 * g2 + 0] = bv[0];
        acc2[t2][4 * g2 + 1] = bv[1];
        acc2[t2][4 * g2 + 2] = bv[2];
        acc2[t2][4 * g2 + 3] = bv[3];
      }
    }

#pragma unroll
    for (int kk2 = 0; kk2 < 16; ++kk2) {
      const int t = kk2 >> 1, q = kk2 & 1;
      auto r0 = __builtin_amdgcn_permlane32_swap(P[t][q][0][0], P[t][q][1][0], false, false);
      auto r1 = __builtin_amdgcn_permlane32_swap(P[t][q][0][1], P[t][q][1][1], false, false);
      union { unsigned uu[4]; bf16x8 v; } bb;
      bb.uu[0] = r0[0]; bb.uu[1] = r1[0]; bb.uu[2] = r0[1]; bb.uu[3] = r1[1];
#pragma unroll
      for (int t2 = 0; t2 < 4; ++t2) {
        bf16x8 afrag = *reinterpret_cast<const bf16x8*>(
            &sW2[kk2 * 2048 + t2 * 512 + lane * 8]);
        acc2[t2] = __builtin_amdgcn_mfma_f32_32x32x16_bf16(afrag, bb.v, acc2[t2], 0, 0, 0);
      }
    }

    // ---------------- Layer 3: dot with W3, sigmoid, blend ----------------
    float part = 0.f;
#pragma unroll
    for (int t2 = 0; t2 < 4; ++t2) {
#pragma unroll
      for (int g2 = 0; g2 < 4; ++g2) {
        f32x4 w3v = *reinterpret_cast<const f32x4*>(&sW3[32 * t2 + 8 * g2 + 4 * hi]);
        part += fmaxf(acc2[t2][4 * g2 + 0], 0.f) * w3v[0]
              + fmaxf(acc2[t2][4 * g2 + 1], 0.f) * w3v[1]
              + fmaxf(acc2[t2][4 * g2 + 2], 0.f) * w3v[2]
              + fmaxf(acc2[t2][4 * g2 + 3], 0.f) * w3v[3];
      }
    }
    part += __shfl_xor(part, 32, 64);  // combine k2-mod-8 halves
    rsum += __shfl_xor(rsum, 32, 64);  // combine n-mod-16 halves

    const float x     = part + b3[m];
    const float ratio = 1.0f / (1.0f + __expf(-x));
    const size_t oi   = (size_t)row * M_ + m;
    const float fw    = last_fw[oi] + rsum;
    const float lf    = last_flow[oi];
    const float flow  = fw * ratio + lf * (1.0f - ratio);
    if (hi == 0) {
      out[oi]        = fw - flow;   // new_free_water
      out[BM_ + oi]  = flow;        // flow
    }
  }
}

// ---------------------------------------------------------------------------
extern "C" void kernel_launch(void* const* d_in, const int* in_sizes, int n_in,
                              void* d_out, int out_size, void* d_ws, size_t ws_size,
                              hipStream_t stream) {
  const float* last_flow = (const float*)d_in[0];
  const float* last_fw   = (const float*)d_in[1];
  const float* runoff    = (const float*)d_in[2];
  const float* W1 = (const float*)d_in[3];
  const float* b1 = (const float*)d_in[4];
  const float* W2 = (const float*)d_in[5];
  const float* b2 = (const float*)d_in[6];
  const float* W3 = (const float*)d_in[7];
  const float* b3 = (const float*)d_in[8];
  float* out = (float*)d_out;

  bf16_t* w1s = (bf16_t*)d_ws;                    // 3*65536 bf16 = 384 KB
  bf16_t* w2s = w1s + (size_t)M_ * 65536;         // 3*32768 bf16 = 192 KB

  prep_weights<<<144, 256, 0, stream>>>(W1, W2, w1s, w2s);

  reservoir_kernel<<<768, 256, 0, stream>>>(last_flow, last_fw, runoff,
                                            b1, b2, W3, b3, w1s, w2s, out);
}